// Round 9
// baseline (1362.267 us; speedup 1.0000x reference)
//
#include <hip/hip_runtime.h>

// ConcentrationPredictor: 32 RK4 steps of dc/dt = flux(c), per-cell MLP D_eff.
// R9 = R2's proven structure (scalar, 1 cell/thread, per-stage __syncthreads,
// free device functions, TPB=256, S_FUSE=4) + two changes:
//  1) amdgpu_waves_per_eu(1,2): the grid is occupancy-limited (1.14 waves/SIMD)
//     so the compiler's default high-occupancy register target (VGPR=32) only
//     serializes the 15 independent neuron chains. Relax it -> interleave.
//  2) pre-scaled weights (scale, 2*log2e, -log2e, D0 folded) via prep kernel:
//     removes ~90 VALU ops/stage and the muls feeding every transcendental.

constexpr int TPB    = 256;              // threads per block = window cells
constexpr int S_FUSE = 4;                // RK4 steps fused per launch
constexpr int HALO   = 4 * S_FUSE;       // validity shrinks 4 cells/side per step
constexpr int B_INNER = TPB - 2 * HALO;  // cells written per block (224)

// d_ws / LDS float layout (rows padded to 16)
constexpr int O_W1 = 0;     // [15] W1*scale*2log2e
constexpr int O_B1 = 16;    // [15] b1*2log2e
constexpr int O_W2 = 32;    // [15][16] transposed, *2log2e
constexpr int O_B2 = 272;   // [15] *2log2e
constexpr int O_W3 = 288;   // [15][16] transposed, *2log2e
constexpr int O_B3 = 528;   // [15] *2log2e
constexpr int O_W4 = 544;   // [15] *(-log2e)
constexpr int O_B4 = 560;   // [1]  *(-log2e)
constexpr int WTOT = 576;

// tanh with input pre-scaled by 2*log2(e): tanh = 1 - 2/(1+2^a)
__device__ __forceinline__ float tanh_pre(float a) {
    float e = __builtin_amdgcn_exp2f(a);
    return fmaf(-2.0f, __builtin_amdgcn_rcpf(1.0f + e), 1.0f);
}

// MLP [1,15,15,15,1]; w = LDS pointer, all scaling folded into weights.
__device__ __forceinline__ float mlp_ret(float x, const float* w)
{
    float h[15], h2[15];
#pragma unroll
    for (int j = 0; j < 15; ++j)
        h[j] = tanh_pre(fmaf(x, w[O_W1 + j], w[O_B1 + j]));
#pragma unroll
    for (int j = 0; j < 15; ++j) {
        float a = w[O_B2 + j];
#pragma unroll
        for (int k = 0; k < 15; ++k) a = fmaf(h[k], w[O_W2 + j * 16 + k], a);
        h2[j] = tanh_pre(a);
    }
#pragma unroll
    for (int j = 0; j < 15; ++j) {
        float a = w[O_B3 + j];
#pragma unroll
        for (int k = 0; k < 15; ++k) a = fmaf(h2[k], w[O_W3 + j * 16 + k], a);
        h[j] = tanh_pre(a);
    }
    float o = w[O_B4];
#pragma unroll
    for (int k = 0; k < 15; ++k) o = fmaf(h[k], w[O_W4 + k], o);
    return __builtin_amdgcn_rcpf(1.0f + __builtin_amdgcn_exp2f(o)); // sigmoid
}

// flux/D0 (D0 folded into the dt coefficient at the combine)
__device__ __forceinline__ float flux_cell(float ret, float c, float cl, float cr,
                                           int g, int N)
{
    if (g == 0)
        return ret * ((1.0f - c) + (cr - c));
    if (g == N - 1) {
        float rbc = 0.0125f * (cl - c);   // D0*DX*(c[N-2]-c[N-1])
        return ret * ((cl - c) + (rbc - c));
    }
    return ret * (cl + cr - 2.0f * c);
}

// prep: scale & transpose weights into d_ws (deterministic, runs every call)
__global__ __launch_bounds__(256)
void prep_kernel(const float* __restrict__ W1, const float* __restrict__ b1,
                 const float* __restrict__ W2, const float* __restrict__ b2,
                 const float* __restrict__ W3, const float* __restrict__ b3,
                 const float* __restrict__ W4, const float* __restrict__ b4,
                 const float* __restrict__ p_exp, float* __restrict__ ws)
{
    const int tid = threadIdx.x;
    const float K1 = 2.8853900817779268f;   // 2*log2(e)
    const float KS = -1.4426950408889634f;  // -log2(e)
    const float scale = __builtin_amdgcn_exp2f(p_exp[0] * 3.321928094887362f); // 10^p

    for (int i = tid; i < WTOT; i += 256) ws[i] = 0.0f;
    __syncthreads();

    if (tid < 15) {
        ws[O_W1 + tid] = W1[tid] * scale * K1;
        ws[O_B1 + tid] = b1[tid] * K1;
        ws[O_B2 + tid] = b2[tid] * K1;
        ws[O_B3 + tid] = b3[tid] * K1;
        ws[O_W4 + tid] = W4[tid] * KS;
    }
    if (tid == 0) ws[O_B4] = b4[0] * KS;
    if (tid < 225) {
        const int k = tid / 15, j = tid % 15;
        ws[O_W2 + j * 16 + k] = W2[tid] * K1;
        ws[O_W3 + j * 16 + k] = W3[tid] * K1;
    }
}

__global__ __launch_bounds__(TPB) __attribute__((amdgpu_waves_per_eu(1, 2)))
void rk4_steps_kernel(const float* __restrict__ src,   // state at step s0 [N]
                      float* __restrict__ out,         // [T, N]
                      const float* __restrict__ t,
                      const float* __restrict__ wsrc,  // prescaled weights
                      int N, int s0, int nsub)
{
    __shared__ float la[TPB];
    __shared__ float lb[TPB];
    __shared__ float w[WTOT];

    const int tid = threadIdx.x;
    for (int i = tid; i < WTOT; i += TPB) w[i] = wsrc[i];

    const int g  = blockIdx.x * B_INNER - HALO + tid;  // my global cell (may be OOB)
    const int gi = min(max(g, 0), N - 1);              // clamped load index

    float c = src[gi];

    const int tl = (tid > 0) ? tid - 1 : 0;
    const int tr = (tid < TPB - 1) ? tid + 1 : TPB - 1;

    for (int s = 0; s < nsub; ++s) {
        const float dt = t[s0 + s + 1] - t[s0 + s];
        const float A  = dt * 0.3125f;                 // dt*D0

        // stage 1 (first barrier also covers the weight staging)
        la[tid] = c;
        __syncthreads();
        float cl = la[tl], cr = la[tr];
        float k1 = flux_cell(mlp_ret(c, w), c, cl, cr, g, N);
        float c2 = fmaf(0.5f * A, k1, c);

        // stage 2
        lb[tid] = c2;
        __syncthreads();
        cl = lb[tl]; cr = lb[tr];
        float k2 = flux_cell(mlp_ret(c2, w), c2, cl, cr, g, N);
        float c3 = fmaf(0.5f * A, k2, c);

        // stage 3
        la[tid] = c3;
        __syncthreads();
        cl = la[tl]; cr = la[tr];
        float k3 = flux_cell(mlp_ret(c3, w), c3, cl, cr, g, N);
        float c4 = fmaf(A, k3, c);

        // stage 4
        lb[tid] = c4;
        __syncthreads();
        cl = lb[tl]; cr = lb[tr];
        float k4 = flux_cell(mlp_ret(c4, w), c4, cl, cr, g, N);

        c = fmaf(A * (1.0f / 6.0f), k1 + 2.0f * (k2 + k3) + k4, c);

        // write valid inner window of this step's new state
        if (tid >= HALO && tid < HALO + B_INNER && g < N)
            out[(size_t)(s0 + s + 1) * N + g] = c;
    }
}

extern "C" void kernel_launch(void* const* d_in, const int* in_sizes, int n_in,
                              void* d_out, int out_size, void* d_ws, size_t ws_size,
                              hipStream_t stream)
{
    const float* c0    = (const float*)d_in[0];
    const float* t     = (const float*)d_in[1];
    const float* W1    = (const float*)d_in[2];
    const float* b1    = (const float*)d_in[3];
    const float* W2    = (const float*)d_in[4];
    const float* b2    = (const float*)d_in[5];
    const float* W3    = (const float*)d_in[6];
    const float* b3    = (const float*)d_in[7];
    const float* W4    = (const float*)d_in[8];
    const float* b4    = (const float*)d_in[9];
    const float* p_exp = (const float*)d_in[10];

    float* out = (float*)d_out;
    float* ws  = (float*)d_ws;

    const int N      = in_sizes[0];       // 65536
    const int nsteps = in_sizes[1] - 1;   // 32

    hipMemcpyAsync(out, c0, (size_t)N * sizeof(float),
                   hipMemcpyDeviceToDevice, stream);

    hipLaunchKernelGGL(prep_kernel, dim3(1), dim3(256), 0, stream,
                       W1, b1, W2, b2, W3, b3, W4, b4, p_exp, ws);

    const int grid = (N + B_INNER - 1) / B_INNER;  // 293

    for (int s0 = 0; s0 < nsteps; s0 += S_FUSE) {
        const int nsub = min(S_FUSE, nsteps - s0);
        const float* src = (s0 == 0) ? c0 : out + (size_t)s0 * N;
        hipLaunchKernelGGL(rk4_steps_kernel, dim3(grid), dim3(TPB), 0, stream,
                           src, out, t, ws, N, s0, nsub);
    }
}

// Round 10
// 92.762 us; speedup vs baseline: 14.6857x; 14.6857x over previous
//
#include <hip/hip_runtime.h>
#include <math.h>

// ConcentrationPredictor: 32 RK4 steps of dc/dt = flux(c), per-cell MLP D_eff.
// R10: the MLP ret(y) is a fixed 1-D function per launch -> precompute a
// cubic-Hermite lookup table in u = asinh(y) space (uniform h=1/128 over
// [-22,22]; tanh features have width >= ~0.25 in u regardless of weight
// magnitude, so interp err ~1e-7 rel). Per cell-stage: ~16 VALU + 2 ds_read_b64
// instead of 480 FMA + 45 tanh + ~130 ds_read (R2's measured bottleneck).
// rk4 kernel keeps R2's exact spill-free structure (scalar, per-stage
// __syncthreads, TPB=256, S_FUSE=4).

constexpr int TPB     = 256;
constexpr int S_FUSE  = 4;
constexpr int HALO    = 4 * S_FUSE;        // 16
constexpr int B_INNER = TPB - 2 * HALO;    // 224

constexpr int   NTAB  = 5633;              // nodes: u in [-22,22], h = 1/128
constexpr float U_MIN = -22.0f;
constexpr float HINV  = 128.0f;            // 1/h
constexpr float HSTEP = 0.0078125f;        // h = 1/128

// ---------- prep: build ret table (value + d/du) with accurate math ----------
__global__ __launch_bounds__(256)
void build_tab_kernel(const float* __restrict__ W1, const float* __restrict__ b1,
                      const float* __restrict__ W2, const float* __restrict__ b2,
                      const float* __restrict__ W3, const float* __restrict__ b3,
                      const float* __restrict__ W4, const float* __restrict__ b4,
                      const float* __restrict__ p_exp, float2* __restrict__ tab)
{
    const int i = blockIdx.x * blockDim.x + threadIdx.x;
    if (i > NTAB) return;
    if (i == NTAB) {               // aux slot: scale = 10^p_exp
        tab[NTAB] = make_float2(powf(10.0f, p_exp[0]), 0.0f);
        return;
    }
    const float u  = U_MIN + (float)i * HSTEP;
    const float y  = sinhf(u);     // MLP input at this node
    const float yd = coshf(u);     // dy/du

    float h[15], hd[15], g[15], gd[15];
#pragma unroll
    for (int j = 0; j < 15; ++j) {
        float a  = fmaf(y, W1[j], b1[j]);
        float ad = yd * W1[j];
        float th = tanhf(a);
        h[j]  = th;
        hd[j] = (1.0f - th * th) * ad;
    }
#pragma unroll
    for (int j = 0; j < 15; ++j) {
        float a = b2[j], ad = 0.0f;
#pragma unroll
        for (int k = 0; k < 15; ++k) {
            a  = fmaf(h[k],  W2[k * 15 + j], a);
            ad = fmaf(hd[k], W2[k * 15 + j], ad);
        }
        float th = tanhf(a);
        g[j]  = th;
        gd[j] = (1.0f - th * th) * ad;
    }
#pragma unroll
    for (int j = 0; j < 15; ++j) {
        float a = b3[j], ad = 0.0f;
#pragma unroll
        for (int k = 0; k < 15; ++k) {
            a  = fmaf(g[k],  W3[k * 15 + j], a);
            ad = fmaf(gd[k], W3[k * 15 + j], ad);
        }
        float th = tanhf(a);
        h[j]  = th;
        hd[j] = (1.0f - th * th) * ad;
    }
    float o = b4[0], od = 0.0f;
#pragma unroll
    for (int k = 0; k < 15; ++k) {
        o  = fmaf(h[k],  W4[k], o);
        od = fmaf(hd[k], W4[k], od);
    }
    const float s = 1.0f / (1.0f + expf(-o));     // sigmoid
    tab[i] = make_float2(s, s * (1.0f - s) * od); // (ret, dret/du)
}

// ---------- table evaluation: ret(c*scale) via asinh + cubic Hermite ----------
__device__ __forceinline__ float ret_tab(float c, float scale,
                                         const float2* __restrict__ tab)
{
    const float y  = c * scale;
    const float ay = fabsf(y);
    // u = asinh(y) = sign(y) * ln(|y| + sqrt(y^2+1)); v_log_f32 is log2 -> *ln2
    const float w  = ay + __builtin_amdgcn_sqrtf(fmaf(ay, ay, 1.0f));
    float u        = __builtin_amdgcn_logf(w) * 0.6931471805599453f;
    u = copysignf(u, y);

    float v = fmaf(u, HINV, -U_MIN * HINV);                 // (u - U_MIN)/h
    v = fminf(fmaxf(v, 0.0f), (float)(NTAB - 2) + 0.999f);  // clamp to table
    const int   i   = (int)v;
    const float tau = v - (float)i;

    const float2 A = tab[i];
    const float2 B = tab[i + 1];
    const float t2 = tau * tau;
    const float t3 = t2 * tau;
    // cubic Hermite with segment length HSTEP
    return A.x * (2.0f * t3 - 3.0f * t2 + 1.0f)
         + B.x * (3.0f * t2 - 2.0f * t3)
         + HSTEP * (A.y * (t3 - 2.0f * t2 + tau) + B.y * (t3 - t2));
}

// flux/D0 (D0 folded into the dt coefficient at the combine)
__device__ __forceinline__ float flux_cell(float ret, float c, float cl, float cr,
                                           int g, int N)
{
    if (g == 0)
        return ret * ((1.0f - c) + (cr - c));
    if (g == N - 1) {
        float rbc = 0.0125f * (cl - c);   // D0*DX*(c[N-2]-c[N-1])
        return ret * ((cl - c) + (rbc - c));
    }
    return ret * (cl + cr - 2.0f * c);
}

__global__ __launch_bounds__(TPB)
void rk4_steps_kernel(const float* __restrict__ src,   // state at step s0 [N]
                      float* __restrict__ out,         // [T, N]
                      const float* __restrict__ t,
                      const float2* __restrict__ tabg, // table in d_ws
                      int N, int s0, int nsub)
{
    __shared__ float2 tab[NTAB + 1];
    __shared__ float  la[TPB];
    __shared__ float  lb[TPB];

    const int tid = threadIdx.x;
    for (int i = tid; i < NTAB + 1; i += TPB) tab[i] = tabg[i];

    const int g  = blockIdx.x * B_INNER - HALO + tid;  // my global cell (may be OOB)
    const int gi = min(max(g, 0), N - 1);              // clamped load index

    float c = src[gi];

    const int tl = (tid > 0) ? tid - 1 : 0;
    const int tr = (tid < TPB - 1) ? tid + 1 : TPB - 1;

    __syncthreads();                  // table staged
    const float scale = tab[NTAB].x;  // uniform broadcast from LDS

    for (int s = 0; s < nsub; ++s) {
        const float dt = t[s0 + s + 1] - t[s0 + s];
        const float A  = dt * 0.3125f;                 // dt*D0

        // stage 1
        la[tid] = c;
        __syncthreads();
        float cl = la[tl], cr = la[tr];
        float k1 = flux_cell(ret_tab(c, scale, tab), c, cl, cr, g, N);
        float c2 = fmaf(0.5f * A, k1, c);

        // stage 2
        lb[tid] = c2;
        __syncthreads();
        cl = lb[tl]; cr = lb[tr];
        float k2 = flux_cell(ret_tab(c2, scale, tab), c2, cl, cr, g, N);
        float c3 = fmaf(0.5f * A, k2, c);

        // stage 3
        la[tid] = c3;
        __syncthreads();
        cl = la[tl]; cr = la[tr];
        float k3 = flux_cell(ret_tab(c3, scale, tab), c3, cl, cr, g, N);
        float c4 = fmaf(A, k3, c);

        // stage 4
        lb[tid] = c4;
        __syncthreads();
        cl = lb[tl]; cr = lb[tr];
        float k4 = flux_cell(ret_tab(c4, scale, tab), c4, cl, cr, g, N);

        c = fmaf(A * (1.0f / 6.0f), k1 + 2.0f * (k2 + k3) + k4, c);

        // write valid inner window of this step's new state
        if (tid >= HALO && tid < HALO + B_INNER && g < N)
            out[(size_t)(s0 + s + 1) * N + g] = c;
    }
}

extern "C" void kernel_launch(void* const* d_in, const int* in_sizes, int n_in,
                              void* d_out, int out_size, void* d_ws, size_t ws_size,
                              hipStream_t stream)
{
    const float* c0    = (const float*)d_in[0];
    const float* t     = (const float*)d_in[1];
    const float* W1    = (const float*)d_in[2];
    const float* b1    = (const float*)d_in[3];
    const float* W2    = (const float*)d_in[4];
    const float* b2    = (const float*)d_in[5];
    const float* W3    = (const float*)d_in[6];
    const float* b3    = (const float*)d_in[7];
    const float* W4    = (const float*)d_in[8];
    const float* b4    = (const float*)d_in[9];
    const float* p_exp = (const float*)d_in[10];

    float*  out = (float*)d_out;
    float2* tab = (float2*)d_ws;   // (NTAB+1) * 8 B = 45072 B

    const int N      = in_sizes[0];       // 65536
    const int nsteps = in_sizes[1] - 1;   // 32

    // row 0 = c0
    hipMemcpyAsync(out, c0, (size_t)N * sizeof(float),
                   hipMemcpyDeviceToDevice, stream);

    // build ret table
    const int tgrid = (NTAB + 1 + 255) / 256;
    hipLaunchKernelGGL(build_tab_kernel, dim3(tgrid), dim3(256), 0, stream,
                       W1, b1, W2, b2, W3, b3, W4, b4, p_exp, tab);

    const int grid = (N + B_INNER - 1) / B_INNER;  // 293

    for (int s0 = 0; s0 < nsteps; s0 += S_FUSE) {
        const int nsub = min(S_FUSE, nsteps - s0);
        const float* src = (s0 == 0) ? c0 : out + (size_t)s0 * N;
        hipLaunchKernelGGL(rk4_steps_kernel, dim3(grid), dim3(TPB), 0, stream,
                           src, out, t, tab, N, s0, nsub);
    }
}

// Round 11
// 67.878 us; speedup vs baseline: 20.0694x; 1.3666x over previous
//
#include <hip/hip_runtime.h>
#include <math.h>

// ConcentrationPredictor: 32 RK4 steps of dc/dt = flux(c), per-cell MLP D_eff.
// R11 = R10 (asinh-space cubic-Hermite table for ret(y)) with:
//  - S_FUSE 4->8: 4 launches (halo 32, inner 192, grid 342), halves launch
//    overhead + table-staging passes; +17% stage-work (we're latency-bound,
//    20x above issue floor, so redundancy is near-free).
//  - row-0 output written by the first rk4 launch (memcpy removed).
//  - ret_tab index fold: v = fma(log2(w), +-ln2*128, 2816)  (one FMA).
//  - float4-vectorized table staging.

constexpr int TPB     = 256;
constexpr int S_FUSE  = 8;
constexpr int HALO    = 4 * S_FUSE;        // 32
constexpr int B_INNER = TPB - 2 * HALO;    // 192

constexpr int   NTAB   = 5633;             // nodes: u in [-22,22], h = 1/128
constexpr float VSLOPE = 88.72283911167299f;  // ln2 * 128
constexpr float VOFF   = 2816.0f;             // -U_MIN * 128
constexpr float HSTEP  = 0.0078125f;          // h = 1/128

// ---------- prep: build ret table (value + d/du) with accurate math ----------
__global__ __launch_bounds__(256)
void build_tab_kernel(const float* __restrict__ W1, const float* __restrict__ b1,
                      const float* __restrict__ W2, const float* __restrict__ b2,
                      const float* __restrict__ W3, const float* __restrict__ b3,
                      const float* __restrict__ W4, const float* __restrict__ b4,
                      const float* __restrict__ p_exp, float2* __restrict__ tab)
{
    const int i = blockIdx.x * blockDim.x + threadIdx.x;
    if (i > NTAB) return;
    if (i == NTAB) {               // aux slot: scale = 10^p_exp
        tab[NTAB] = make_float2(powf(10.0f, p_exp[0]), 0.0f);
        return;
    }
    const float u  = -22.0f + (float)i * HSTEP;
    const float y  = sinhf(u);     // MLP input at this node
    const float yd = coshf(u);     // dy/du

    float h[15], hd[15], g[15], gd[15];
#pragma unroll
    for (int j = 0; j < 15; ++j) {
        float a  = fmaf(y, W1[j], b1[j]);
        float ad = yd * W1[j];
        float th = tanhf(a);
        h[j]  = th;
        hd[j] = (1.0f - th * th) * ad;
    }
#pragma unroll
    for (int j = 0; j < 15; ++j) {
        float a = b2[j], ad = 0.0f;
#pragma unroll
        for (int k = 0; k < 15; ++k) {
            a  = fmaf(h[k],  W2[k * 15 + j], a);
            ad = fmaf(hd[k], W2[k * 15 + j], ad);
        }
        float th = tanhf(a);
        g[j]  = th;
        gd[j] = (1.0f - th * th) * ad;
    }
#pragma unroll
    for (int j = 0; j < 15; ++j) {
        float a = b3[j], ad = 0.0f;
#pragma unroll
        for (int k = 0; k < 15; ++k) {
            a  = fmaf(g[k],  W3[k * 15 + j], a);
            ad = fmaf(gd[k], W3[k * 15 + j], ad);
        }
        float th = tanhf(a);
        h[j]  = th;
        hd[j] = (1.0f - th * th) * ad;
    }
    float o = b4[0], od = 0.0f;
#pragma unroll
    for (int k = 0; k < 15; ++k) {
        o  = fmaf(h[k],  W4[k], o);
        od = fmaf(hd[k], W4[k], od);
    }
    const float s = 1.0f / (1.0f + expf(-o));     // sigmoid
    tab[i] = make_float2(s, s * (1.0f - s) * od); // (ret, dret/du)
}

// ---------- table evaluation: ret(c*scale) via asinh + cubic Hermite ----------
__device__ __forceinline__ float ret_tab(float c, float scale,
                                         const float2* __restrict__ tab)
{
    const float y  = c * scale;
    const float ay = fabsf(y);
    // u = asinh(y); v = (u + 22)*128 folded into one fma off v_log_f32 (log2):
    // v = sign(y)*log2(|y|+sqrt(y^2+1))*(ln2*128) + 2816
    const float w  = ay + __builtin_amdgcn_sqrtf(fmaf(ay, ay, 1.0f));
    const float m  = copysignf(VSLOPE, y);
    float v = fmaf(__builtin_amdgcn_logf(w), m, VOFF);
    v = fminf(fmaxf(v, 0.0f), (float)(NTAB - 2) + 0.999f);  // clamp to table
    const int   i   = (int)v;
    const float tau = v - (float)i;

    const float2 A = tab[i];
    const float2 B = tab[i + 1];
    const float t2 = tau * tau;
    const float t3 = t2 * tau;
    // cubic Hermite with segment length HSTEP
    return A.x * (2.0f * t3 - 3.0f * t2 + 1.0f)
         + B.x * (3.0f * t2 - 2.0f * t3)
         + HSTEP * (A.y * (t3 - 2.0f * t2 + tau) + B.y * (t3 - t2));
}

// flux/D0 (D0 folded into the dt coefficient at the combine)
__device__ __forceinline__ float flux_cell(float ret, float c, float cl, float cr,
                                           int g, int N)
{
    if (g == 0)
        return ret * ((1.0f - c) + (cr - c));
    if (g == N - 1) {
        float rbc = 0.0125f * (cl - c);   // D0*DX*(c[N-2]-c[N-1])
        return ret * ((cl - c) + (rbc - c));
    }
    return ret * (cl + cr - 2.0f * c);
}

__global__ __launch_bounds__(TPB)
void rk4_steps_kernel(const float* __restrict__ src,   // state at step s0 [N]
                      float* __restrict__ out,         // [T, N]
                      const float* __restrict__ t,
                      const float2* __restrict__ tabg, // table in d_ws
                      int N, int s0, int nsub)
{
    __shared__ float2 tab[NTAB + 1];
    __shared__ float  la[TPB];
    __shared__ float  lb[TPB];

    const int tid = threadIdx.x;

    // stage table, float4-vectorized ((NTAB+1)/2 = 2817 float4s)
    {
        const float4* __restrict__ s4 = (const float4*)tabg;
        float4* d4 = (float4*)tab;
        for (int i = tid; i < (NTAB + 1) / 2; i += TPB) d4[i] = s4[i];
        if (tid == 0) tab[NTAB] = tabg[NTAB];   // odd tail entry
    }

    const int g  = blockIdx.x * B_INNER - HALO + tid;  // my global cell (may be OOB)
    const int gi = min(max(g, 0), N - 1);              // clamped load index

    float c = src[gi];

    const int  tl    = (tid > 0) ? tid - 1 : 0;
    const int  tr    = (tid < TPB - 1) ? tid + 1 : TPB - 1;
    const bool valid = (tid >= HALO) && (tid < HALO + B_INNER) && (g < N);

    // first launch also writes row 0 (replaces the D2D memcpy)
    if (s0 == 0 && valid) out[g] = c;

    __syncthreads();                  // table staged
    const float scale = tab[NTAB].x;  // uniform broadcast from LDS

    for (int s = 0; s < nsub; ++s) {
        const float dt = t[s0 + s + 1] - t[s0 + s];
        const float A  = dt * 0.3125f;                 // dt*D0

        // stage 1
        la[tid] = c;
        __syncthreads();
        float cl = la[tl], cr = la[tr];
        float k1 = flux_cell(ret_tab(c, scale, tab), c, cl, cr, g, N);
        float c2 = fmaf(0.5f * A, k1, c);

        // stage 2
        lb[tid] = c2;
        __syncthreads();
        cl = lb[tl]; cr = lb[tr];
        float k2 = flux_cell(ret_tab(c2, scale, tab), c2, cl, cr, g, N);
        float c3 = fmaf(0.5f * A, k2, c);

        // stage 3
        la[tid] = c3;
        __syncthreads();
        cl = la[tl]; cr = la[tr];
        float k3 = flux_cell(ret_tab(c3, scale, tab), c3, cl, cr, g, N);
        float c4 = fmaf(A, k3, c);

        // stage 4
        lb[tid] = c4;
        __syncthreads();
        cl = lb[tl]; cr = lb[tr];
        float k4 = flux_cell(ret_tab(c4, scale, tab), c4, cl, cr, g, N);

        c = fmaf(A * (1.0f / 6.0f), k1 + 2.0f * (k2 + k3) + k4, c);

        // write valid inner window of this step's new state
        if (valid)
            out[(size_t)(s0 + s + 1) * N + g] = c;
    }
}

extern "C" void kernel_launch(void* const* d_in, const int* in_sizes, int n_in,
                              void* d_out, int out_size, void* d_ws, size_t ws_size,
                              hipStream_t stream)
{
    const float* c0    = (const float*)d_in[0];
    const float* t     = (const float*)d_in[1];
    const float* W1    = (const float*)d_in[2];
    const float* b1    = (const float*)d_in[3];
    const float* W2    = (const float*)d_in[4];
    const float* b2    = (const float*)d_in[5];
    const float* W3    = (const float*)d_in[6];
    const float* b3    = (const float*)d_in[7];
    const float* W4    = (const float*)d_in[8];
    const float* b4    = (const float*)d_in[9];
    const float* p_exp = (const float*)d_in[10];

    float*  out = (float*)d_out;
    float2* tab = (float2*)d_ws;   // (NTAB+1) * 8 B = 45072 B

    const int N      = in_sizes[0];       // 65536
    const int nsteps = in_sizes[1] - 1;   // 32

    // build ret table
    const int tgrid = (NTAB + 1 + 255) / 256;
    hipLaunchKernelGGL(build_tab_kernel, dim3(tgrid), dim3(256), 0, stream,
                       W1, b1, W2, b2, W3, b3, W4, b4, p_exp, tab);

    const int grid = (N + B_INNER - 1) / B_INNER;  // 342

    for (int s0 = 0; s0 < nsteps; s0 += S_FUSE) {
        const int nsub = min(S_FUSE, nsteps - s0);
        const float* src = (s0 == 0) ? c0 : out + (size_t)s0 * N;
        hipLaunchKernelGGL(rk4_steps_kernel, dim3(grid), dim3(TPB), 0, stream,
                           src, out, t, tab, N, s0, nsub);
    }
}

// Round 12
// 59.939 us; speedup vs baseline: 22.7274x; 1.1324x over previous
//
#include <hip/hip_runtime.h>
#include <math.h>

// ConcentrationPredictor: 32 RK4 steps of dc/dt = flux(c), per-cell MLP D_eff.
// R12 = R11 (asinh-space cubic-Hermite table for ret(y)) collapsed to ONE rk4
// dispatch: TPB=512, S_FUSE=32 (halo 128/side, inner 256, grid 256 = 1
// block/CU, 2 waves/SIMD). Dispatch count 5 -> 2 (~5us marginal each), table
// staged once total, double the TLP for gather-latency hiding; redundancy
// 1.33x -> 2x (cheap: stage issue-work is ~5x below the latency path).

constexpr int TPB     = 512;
constexpr int S_FUSE  = 32;
constexpr int HALO    = 4 * S_FUSE;        // 128
constexpr int B_INNER = TPB - 2 * HALO;    // 256

constexpr int   NTAB   = 5633;             // nodes: u in [-22,22], h = 1/128
constexpr float VSLOPE = 88.72283911167299f;  // ln2 * 128
constexpr float VOFF   = 2816.0f;             // -U_MIN * 128
constexpr float HSTEP  = 0.0078125f;          // h = 1/128

// ---------- prep: build ret table (value + d/du) with accurate math ----------
__global__ __launch_bounds__(256)
void build_tab_kernel(const float* __restrict__ W1, const float* __restrict__ b1,
                      const float* __restrict__ W2, const float* __restrict__ b2,
                      const float* __restrict__ W3, const float* __restrict__ b3,
                      const float* __restrict__ W4, const float* __restrict__ b4,
                      const float* __restrict__ p_exp, float2* __restrict__ tab)
{
    const int i = blockIdx.x * blockDim.x + threadIdx.x;
    if (i > NTAB) return;
    if (i == NTAB) {               // aux slot: scale = 10^p_exp
        tab[NTAB] = make_float2(powf(10.0f, p_exp[0]), 0.0f);
        return;
    }
    const float u  = -22.0f + (float)i * HSTEP;
    const float y  = sinhf(u);     // MLP input at this node
    const float yd = coshf(u);     // dy/du

    float h[15], hd[15], g[15], gd[15];
#pragma unroll
    for (int j = 0; j < 15; ++j) {
        float a  = fmaf(y, W1[j], b1[j]);
        float ad = yd * W1[j];
        float th = tanhf(a);
        h[j]  = th;
        hd[j] = (1.0f - th * th) * ad;
    }
#pragma unroll
    for (int j = 0; j < 15; ++j) {
        float a = b2[j], ad = 0.0f;
#pragma unroll
        for (int k = 0; k < 15; ++k) {
            a  = fmaf(h[k],  W2[k * 15 + j], a);
            ad = fmaf(hd[k], W2[k * 15 + j], ad);
        }
        float th = tanhf(a);
        g[j]  = th;
        gd[j] = (1.0f - th * th) * ad;
    }
#pragma unroll
    for (int j = 0; j < 15; ++j) {
        float a = b3[j], ad = 0.0f;
#pragma unroll
        for (int k = 0; k < 15; ++k) {
            a  = fmaf(g[k],  W3[k * 15 + j], a);
            ad = fmaf(gd[k], W3[k * 15 + j], ad);
        }
        float th = tanhf(a);
        h[j]  = th;
        hd[j] = (1.0f - th * th) * ad;
    }
    float o = b4[0], od = 0.0f;
#pragma unroll
    for (int k = 0; k < 15; ++k) {
        o  = fmaf(h[k],  W4[k], o);
        od = fmaf(hd[k], W4[k], od);
    }
    const float s = 1.0f / (1.0f + expf(-o));     // sigmoid
    tab[i] = make_float2(s, s * (1.0f - s) * od); // (ret, dret/du)
}

// ---------- table evaluation: ret(c*scale) via asinh + cubic Hermite ----------
__device__ __forceinline__ float ret_tab(float c, float scale,
                                         const float2* __restrict__ tab)
{
    const float y  = c * scale;
    const float ay = fabsf(y);
    // u = asinh(y); v = (u + 22)*128 folded into one fma off v_log_f32 (log2):
    // v = sign(y)*log2(|y|+sqrt(y^2+1))*(ln2*128) + 2816
    const float w  = ay + __builtin_amdgcn_sqrtf(fmaf(ay, ay, 1.0f));
    const float m  = copysignf(VSLOPE, y);
    float v = fmaf(__builtin_amdgcn_logf(w), m, VOFF);
    v = fminf(fmaxf(v, 0.0f), (float)(NTAB - 2) + 0.999f);  // clamp to table
    const int   i   = (int)v;
    const float tau = v - (float)i;

    const float2 A = tab[i];
    const float2 B = tab[i + 1];
    const float t2 = tau * tau;
    const float t3 = t2 * tau;
    // cubic Hermite with segment length HSTEP
    return A.x * (2.0f * t3 - 3.0f * t2 + 1.0f)
         + B.x * (3.0f * t2 - 2.0f * t3)
         + HSTEP * (A.y * (t3 - 2.0f * t2 + tau) + B.y * (t3 - t2));
}

// flux/D0 (D0 folded into the dt coefficient at the combine)
__device__ __forceinline__ float flux_cell(float ret, float c, float cl, float cr,
                                           int g, int N)
{
    if (g == 0)
        return ret * ((1.0f - c) + (cr - c));
    if (g == N - 1) {
        float rbc = 0.0125f * (cl - c);   // D0*DX*(c[N-2]-c[N-1])
        return ret * ((cl - c) + (rbc - c));
    }
    return ret * (cl + cr - 2.0f * c);
}

__global__ __launch_bounds__(TPB)
void rk4_steps_kernel(const float* __restrict__ src,   // state at step s0 [N]
                      float* __restrict__ out,         // [T, N]
                      const float* __restrict__ t,
                      const float2* __restrict__ tabg, // table in d_ws
                      int N, int s0, int nsub)
{
    __shared__ float2 tab[NTAB + 1];
    __shared__ float  la[TPB];
    __shared__ float  lb[TPB];

    const int tid = threadIdx.x;

    // stage table, float4-vectorized ((NTAB+1)/2 = 2817 float4s)
    {
        const float4* __restrict__ s4 = (const float4*)tabg;
        float4* d4 = (float4*)tab;
        for (int i = tid; i < (NTAB + 1) / 2; i += TPB) d4[i] = s4[i];
        if (tid == 0) tab[NTAB] = tabg[NTAB];   // odd tail entry
    }

    const int g  = blockIdx.x * B_INNER - HALO + tid;  // my global cell (may be OOB)
    const int gi = min(max(g, 0), N - 1);              // clamped load index

    float c = src[gi];

    const int  tl    = (tid > 0) ? tid - 1 : 0;
    const int  tr    = (tid < TPB - 1) ? tid + 1 : TPB - 1;
    const bool valid = (tid >= HALO) && (tid < HALO + B_INNER) && (g < N);

    // first launch also writes row 0 (replaces the D2D memcpy)
    if (s0 == 0 && valid) out[g] = c;

    __syncthreads();                  // table staged
    const float scale = tab[NTAB].x;  // uniform broadcast from LDS

    for (int s = 0; s < nsub; ++s) {
        const float dt = t[s0 + s + 1] - t[s0 + s];
        const float A  = dt * 0.3125f;                 // dt*D0

        // stage 1
        la[tid] = c;
        __syncthreads();
        float cl = la[tl], cr = la[tr];
        float k1 = flux_cell(ret_tab(c, scale, tab), c, cl, cr, g, N);
        float c2 = fmaf(0.5f * A, k1, c);

        // stage 2
        lb[tid] = c2;
        __syncthreads();
        cl = lb[tl]; cr = lb[tr];
        float k2 = flux_cell(ret_tab(c2, scale, tab), c2, cl, cr, g, N);
        float c3 = fmaf(0.5f * A, k2, c);

        // stage 3
        la[tid] = c3;
        __syncthreads();
        cl = la[tl]; cr = la[tr];
        float k3 = flux_cell(ret_tab(c3, scale, tab), c3, cl, cr, g, N);
        float c4 = fmaf(A, k3, c);

        // stage 4
        lb[tid] = c4;
        __syncthreads();
        cl = lb[tl]; cr = lb[tr];
        float k4 = flux_cell(ret_tab(c4, scale, tab), c4, cl, cr, g, N);

        c = fmaf(A * (1.0f / 6.0f), k1 + 2.0f * (k2 + k3) + k4, c);

        // write valid inner window of this step's new state
        if (valid)
            out[(size_t)(s0 + s + 1) * N + g] = c;
    }
}

extern "C" void kernel_launch(void* const* d_in, const int* in_sizes, int n_in,
                              void* d_out, int out_size, void* d_ws, size_t ws_size,
                              hipStream_t stream)
{
    const float* c0    = (const float*)d_in[0];
    const float* t     = (const float*)d_in[1];
    const float* W1    = (const float*)d_in[2];
    const float* b1    = (const float*)d_in[3];
    const float* W2    = (const float*)d_in[4];
    const float* b2    = (const float*)d_in[5];
    const float* W3    = (const float*)d_in[6];
    const float* b3    = (const float*)d_in[7];
    const float* W4    = (const float*)d_in[8];
    const float* b4    = (const float*)d_in[9];
    const float* p_exp = (const float*)d_in[10];

    float*  out = (float*)d_out;
    float2* tab = (float2*)d_ws;   // (NTAB+1) * 8 B = 45072 B

    const int N      = in_sizes[0];       // 65536
    const int nsteps = in_sizes[1] - 1;   // 32

    // build ret table
    const int tgrid = (NTAB + 1 + 255) / 256;
    hipLaunchKernelGGL(build_tab_kernel, dim3(tgrid), dim3(256), 0, stream,
                       W1, b1, W2, b2, W3, b3, W4, b4, p_exp, tab);

    const int grid = (N + B_INNER - 1) / B_INNER;  // 256

    for (int s0 = 0; s0 < nsteps; s0 += S_FUSE) {   // single iteration for T=33
        const int nsub = min(S_FUSE, nsteps - s0);
        const float* src = (s0 == 0) ? c0 : out + (size_t)s0 * N;
        hipLaunchKernelGGL(rk4_steps_kernel, dim3(grid), dim3(TPB), 0, stream,
                           src, out, t, tab, N, s0, nsub);
    }
}